// Round 8
// baseline (335.098 us; speedup 1.0000x reference)
//
#include <hip/hip_runtime.h>
#include <cstdint>
#include <cstddef>

// ---------------- problem constants ----------------
#define SCALEQ 0.17677669529663689f // 32^-0.5

typedef _Float16 half_t;
typedef _Float16 half8   __attribute__((ext_vector_type(8)));
typedef _Float16 half4v  __attribute__((ext_vector_type(4)));
typedef float    float4v __attribute__((ext_vector_type(4)));

#define GLDS16(gp, lp)                                                        \
  __builtin_amdgcn_global_load_lds(                                           \
      (const __attribute__((address_space(1))) void*)(gp),                    \
      (__attribute__((address_space(3))) void*)(lp), 16, 0, 0)

// ---------------- merged prep kernel (r5-verified) ----------------
__global__ __launch_bounds__(256) void prep_all(
    const float* __restrict__ x, const float* __restrict__ dwconv_w,
    const float* __restrict__ qkv_w, const float* __restrict__ proj_w,
    const float* __restrict__ rpb, half_t* __restrict__ xpad,
    half_t* __restrict__ Wt, half_t* __restrict__ qw16,
    half_t* __restrict__ pw16, float* __restrict__ btab) {
  __shared__ float tile[128 * 65];
  const int blk = blockIdx.x, t = threadIdx.x;
  if (blk < 800) {
    const int bd = blk, b = bd / 100, d = bd % 100;
    for (int hf = 0; hf < 2; ++hf) {
      for (int i = 0; i < 32; ++i) {
        int idx = i * 256 + t, c = idx >> 6, hw = idx & 63;
        tile[c * 65 + hw] = x[(size_t)((b * 256 + hf * 128 + c) * 100 + d) * 64 + hw];
      }
      __syncthreads();
      for (int i = 0; i < 50; ++i) {
        int idx = i * 256 + t, cell = idx >> 7, c = idx & 127;
        int hh = cell / 10, ww = cell % 10;
        float v = 0.f;
        if (hh >= 1 && hh <= 8 && ww >= 1 && ww <= 8)
          v = tile[c * 65 + (hh - 1) * 8 + (ww - 1)];
        xpad[(size_t)(bd * 100 + cell) * 256 + hf * 128 + c] = (half_t)v;
      }
      __syncthreads();
    }
  } else if (blk < 944) {        // convw: Wt[tap][o][c]
    const int base = (blk - 800) * 4096;
#pragma unroll
    for (int i = 0; i < 16; ++i) {
      int idx = base + i * 256 + t;
      int tap = idx >> 16, rem = idx & 65535;
      int o = rem >> 8, c = rem & 255;
      Wt[idx] = (half_t)dwconv_w[(o * 256 + c) * 9 + tap];
    }
  } else if (blk < 1040) {       // qkvw (q rows pre-scaled)
    const int base = (blk - 944) * 2048;
#pragma unroll
    for (int i = 0; i < 8; ++i) {
      int idx = base + i * 256 + t;
      float v = qkv_w[idx];
      if (idx < 65536) v *= SCALEQ;
      qw16[idx] = (half_t)v;
    }
  } else if (blk < 1072) {       // projw
    const int base = (blk - 1040) * 2048;
#pragma unroll
    for (int i = 0; i < 8; ++i) {
      int idx = base + i * 256 + t;
      pw16[idx] = (half_t)proj_w[idx];
    }
  } else {                       // bias table btab[head][n][m]
    const int base = (blk - 1072) * 2048;
#pragma unroll
    for (int i = 0; i < 8; ++i) {
      int idx = base + i * 256 + t;
      int hd = idx >> 12, n = (idx >> 6) & 63, m = idx & 63;
      int h1 = n >> 3, w1 = n & 7, h2 = m >> 3, w2 = m & 7;
      int ridx = (h1 - h2 + 7) * 15 + (w1 - w2 + 7);
      btab[idx] = rpb[ridx * 8 + hd];
    }
  }
}

// ---------------- conv implicit GEMM (unchanged, verified) ----------------
__global__ __launch_bounds__(256) void conv_kernel(
    const half_t* __restrict__ Wt, const half_t* __restrict__ xpad,
    const float* __restrict__ convb, half_t* __restrict__ xl) {
  __shared__ __align__(16) half_t Asm[128 * 64];
  __shared__ __align__(16) half_t Bsm[128 * 64];
  const int blk = blockIdx.x;
  const int o0 = (blk & 1) * 128;
  const int n0 = (blk >> 1) * 128;
  const int tid = threadIdx.x;
  const int wave = tid >> 6, lane = tid & 63;
  const int l15 = lane & 15, quad = lane >> 4;
  const int wm = wave >> 1, wn = wave & 1;
  const int srow = tid >> 3;
  const int cg = (tid & 7) ^ (srow & 7);

  int pixbase[4], arow[4];
#pragma unroll
  for (int i = 0; i < 4; ++i) {
    int P = n0 + srow + i * 32;
    int bd = P >> 6, hw = P & 63;
    pixbase[i] = (bd * 100 + (hw >> 3) * 10 + (hw & 7)) * 512 + cg * 16;
    arow[i] = (o0 + srow + i * 32) * 512 + cg * 16;
  }

  float4v acc[4][4];
#pragma unroll
  for (int mi = 0; mi < 4; ++mi)
#pragma unroll
    for (int ni = 0; ni < 4; ++ni) {
      float4v z = {0.f, 0.f, 0.f, 0.f};
      acc[mi][ni] = z;
    }

  const char* xpc = (const char*)xpad;
  for (int tap = 0; tap < 9; ++tap) {
    const char* wt = (const char*)Wt + tap * 131072;
    const int toff = ((tap / 3) * 10 + (tap % 3)) * 512;
    for (int c0 = 0; c0 < 512; c0 += 128) {
#pragma unroll
      for (int i = 0; i < 4; ++i) {
        GLDS16(wt + arow[i] + c0, (char*)Asm + i * 4096 + wave * 1024);
        GLDS16(xpc + pixbase[i] + toff + c0, (char*)Bsm + i * 4096 + wave * 1024);
      }
      __syncthreads();
#pragma unroll
      for (int kh = 0; kh < 2; ++kh) {
        half8 af[4], bf[4];
#pragma unroll
        for (int mi = 0; mi < 4; ++mi) {
          int r = wm * 64 + mi * 16 + l15;
          af[mi] = *(const half8*)&Asm[r * 64 + (((kh * 4 + quad) ^ (r & 7)) * 8)];
        }
#pragma unroll
        for (int ni = 0; ni < 4; ++ni) {
          int r = wn * 64 + ni * 16 + l15;
          bf[ni] = *(const half8*)&Bsm[r * 64 + (((kh * 4 + quad) ^ (r & 7)) * 8)];
        }
#pragma unroll
        for (int mi = 0; mi < 4; ++mi)
#pragma unroll
          for (int ni = 0; ni < 4; ++ni)
            acc[mi][ni] = __builtin_amdgcn_mfma_f32_16x16x32_f16(
                af[mi], bf[ni], acc[mi][ni], 0, 0, 0);
      }
      __syncthreads();
    }
  }
#pragma unroll
  for (int mi = 0; mi < 4; ++mi) {
    const int o4 = o0 + wm * 64 + mi * 16 + quad * 4;
    const float b0 = convb[o4], b1 = convb[o4 + 1], b2 = convb[o4 + 2], b3 = convb[o4 + 3];
#pragma unroll
    for (int ni = 0; ni < 4; ++ni) {
      const int P = n0 + wn * 64 + ni * 16 + l15;
      half4v h;
      h.x = (half_t)(acc[mi][ni].x + b0);
      h.y = (half_t)(acc[mi][ni].y + b1);
      h.z = (half_t)(acc[mi][ni].z + b2);
      h.w = (half_t)(acc[mi][ni].w + b3);
      *(half4v*)(xl + (size_t)P * 256 + o4) = h;
    }
  }
}

// ---------------- fused qkv + attention + proj, 16 waves ----------------
// grid 800 (one bd slice), block 1024 = 16 waves = 4 waves/SIMD.
// Wave w: head h=w>>1, half=w&1 (pixel/query rows half*32..+32).
// Per-HEAD scratch (7424 halves): q[64][40], k[64][40]@2560, v[32][72]@5120;
// P[64][72] overlays q+k AFTER a block barrier (aq/bk already in regs).
// LDS: xlp [64][256] swizzled @0 (16896h incl. xa [64][264] / T fp32 overlay)
//      + 8 heads x 7424h = 76288 halves = 152.6 KB -> 1 block/CU, 16 waves.
__global__ __launch_bounds__(1024) void fused_tail5(
    const half_t* __restrict__ xlg, const half_t* __restrict__ qw,
    const float* __restrict__ qkvb, const float* __restrict__ btab,
    const half_t* __restrict__ pw, const float* __restrict__ projb,
    float* __restrict__ out32) {
  __shared__ __align__(16) half_t LS[76288];   // 152576 B
  const int bd = blockIdx.x;
  const int tid = threadIdx.x;
  const int wave = tid >> 6, lane = tid & 63;
  const int l15 = lane & 15, quad = lane >> 4;
  const int head = wave >> 1, half = wave & 1;

  half_t* xlp = LS;
  half_t* xa = LS;                      // [64][264] overlay (xlp dead)
  float* T = (float*)LS;                // [64][68] fp32 overlay (xa dead)
  half_t* scr = LS + 16896 + head * 7424;
  half_t* qsc = scr;                    // [64][40]
  half_t* ksc = scr + 2560;             // [64][40]
  half_t* vsc = scr + 5120;             // [32][72]
  half_t* Psc = scr;                    // [64][72] overlays q+k post-barrier

  // ---- stage xl[bd] (32 KB), XOR-swizzled 16B chunks, 2 rows/wave/iter ----
  {
    const char* src = (const char*)(xlg + (size_t)bd * 64 * 256);
#pragma unroll
    for (int i = 0; i < 2; ++i) {
      int row = i * 32 + wave * 2 + (lane >> 5);
      int sch = (lane & 31) ^ (row & 7);
      GLDS16(src + row * 512 + sch * 16, (char*)xlp + (i * 32 + wave * 2) * 512);
    }
  }
  __syncthreads();  // barrier 1: xlp ready

  // ---- qkv: 3 parts, M=32 chans (head), N=32 px (half), K=256 ----
  for (int p = 0; p < 3; ++p) {
    const half_t* Wp = qw + p * 65536 + head * 32 * 256;
    float4v acc[2][2];
#pragma unroll
    for (int mi = 0; mi < 2; ++mi)
#pragma unroll
      for (int ni = 0; ni < 2; ++ni) {
        float4v z = {0.f, 0.f, 0.f, 0.f};
        acc[mi][ni] = z;
      }
#pragma unroll
    for (int kh = 0; kh < 8; ++kh) {
      half8 bf[2], af[2];
#pragma unroll
      for (int ni = 0; ni < 2; ++ni) {
        int r = half * 32 + ni * 16 + l15;
        bf[ni] = *(const half8*)&xlp[r * 256 + (((kh * 4 + quad) ^ (r & 7)) * 8)];
      }
#pragma unroll
      for (int mi = 0; mi < 2; ++mi)
        af[mi] = *(const half8*)(Wp + (mi * 16 + l15) * 256 + kh * 32 + quad * 8);
#pragma unroll
      for (int mi = 0; mi < 2; ++mi)
#pragma unroll
        for (int ni = 0; ni < 2; ++ni)
          acc[mi][ni] = __builtin_amdgcn_mfma_f32_16x16x32_f16(
              af[mi], bf[ni], acc[mi][ni], 0, 0, 0);
    }
    if (p < 2) {
      half_t* dst = (p == 0) ? qsc : ksc;
      const float sc = (p == 0) ? SCALEQ : 1.0f;
#pragma unroll
      for (int mi = 0; mi < 2; ++mi) {
        const float4v b4 = *(const float4v*)&qkvb[p * 256 + head * 32 + mi * 16 + quad * 4];
#pragma unroll
        for (int ni = 0; ni < 2; ++ni) {
          const int px = half * 32 + ni * 16 + l15;
          half4v h;
          h.x = (half_t)(acc[mi][ni].x + b4.x * sc);
          h.y = (half_t)(acc[mi][ni].y + b4.y * sc);
          h.z = (half_t)(acc[mi][ni].z + b4.z * sc);
          h.w = (half_t)(acc[mi][ni].w + b4.w * sc);
          *(half4v*)(dst + px * 40 + mi * 16 + quad * 4) = h;
        }
      }
    } else {
#pragma unroll
      for (int mi = 0; mi < 2; ++mi) {
        const float4v b4 = *(const float4v*)&qkvb[512 + head * 32 + mi * 16 + quad * 4];
#pragma unroll
        for (int ni = 0; ni < 2; ++ni) {
          const int px = half * 32 + ni * 16 + l15;
#pragma unroll
          for (int iv = 0; iv < 4; ++iv)
            vsc[(mi * 16 + quad * 4 + iv) * 72 + px] = (half_t)(acc[mi][ni][iv] + b4[iv]);
        }
      }
    }
  }
  __syncthreads();  // barrier 2: q/k/v complete per head; xlp dead

  // ---- QK^T (32 query rows x 64 keys) + bias + softmax ----
  half8 aq[2], bk[4];
#pragma unroll
  for (int i = 0; i < 2; ++i)
    aq[i] = *(const half8*)(qsc + (half * 32 + i * 16 + l15) * 40 + quad * 8);
#pragma unroll
  for (int i = 0; i < 4; ++i)
    bk[i] = *(const half8*)(ksc + (i * 16 + l15) * 40 + quad * 8);
  float4v s[2][4];
#pragma unroll
  for (int ni = 0; ni < 2; ++ni)
#pragma unroll
    for (int mi = 0; mi < 4; ++mi) {
      float4v z = {0.f, 0.f, 0.f, 0.f};
      s[ni][mi] = __builtin_amdgcn_mfma_f32_16x16x32_f16(aq[ni], bk[mi], z, 0, 0, 0);
    }
  const float* bh = btab + head * 4096;
#pragma unroll
  for (int ni = 0; ni < 2; ++ni)
#pragma unroll
    for (int i = 0; i < 4; ++i) {
      const int n = half * 32 + ni * 16 + quad * 4 + i;
#pragma unroll
      for (int mi = 0; mi < 4; ++mi) s[ni][mi][i] += bh[n * 64 + mi * 16 + l15];
    }
  float inv[2][4];
#pragma unroll
  for (int ni = 0; ni < 2; ++ni)
#pragma unroll
    for (int i = 0; i < 4; ++i) {
      float mx = fmaxf(fmaxf(s[ni][0][i], s[ni][1][i]), fmaxf(s[ni][2][i], s[ni][3][i]));
      for (int off = 1; off < 16; off <<= 1) mx = fmaxf(mx, __shfl_xor(mx, off));
      float sum = 0.f;
#pragma unroll
      for (int mi = 0; mi < 4; ++mi) {
        float e = __expf(s[ni][mi][i] - mx);
        s[ni][mi][i] = e;
        sum += e;
      }
      for (int off = 1; off < 16; off <<= 1) sum += __shfl_xor(sum, off);
      inv[ni][i] = 1.0f / sum;
    }
  __syncthreads();  // barrier 3: all q/k LDS reads done -> P may overlay

#pragma unroll
  for (int ni = 0; ni < 2; ++ni)
#pragma unroll
    for (int i = 0; i < 4; ++i) {
      const int n = half * 32 + ni * 16 + quad * 4 + i;
#pragma unroll
      for (int mi = 0; mi < 4; ++mi)
        Psc[n * 72 + mi * 16 + l15] = (half_t)(s[ni][mi][i] * inv[ni][i]);
    }
  __builtin_amdgcn_s_waitcnt(0);  // P writes -> own reads (rows are wave-own)

  // ---- PV: xa^T(c, n-half) = v(c, m) . P^T(m, n), K=64 ----
  half8 av[2][2];
#pragma unroll
  for (int ci = 0; ci < 2; ++ci)
#pragma unroll
    for (int k2 = 0; k2 < 2; ++k2)
      av[ci][k2] = *(const half8*)(vsc + (ci * 16 + l15) * 72 + k2 * 32 + quad * 8);
  float4v oa[2][2];
#pragma unroll
  for (int ci = 0; ci < 2; ++ci)
#pragma unroll
    for (int ni = 0; ni < 2; ++ni) {
      float4v z = {0.f, 0.f, 0.f, 0.f};
      oa[ci][ni] = z;
    }
#pragma unroll
  for (int ni = 0; ni < 2; ++ni)
#pragma unroll
    for (int k2 = 0; k2 < 2; ++k2) {
      half8 bp = *(const half8*)&Psc[(half * 32 + ni * 16 + l15) * 72 + k2 * 32 + quad * 8];
#pragma unroll
      for (int ci = 0; ci < 2; ++ci)
        oa[ci][ni] = __builtin_amdgcn_mfma_f32_16x16x32_f16(av[ci][k2], bp, oa[ci][ni], 0, 0, 0);
    }

  // ---- xa -> LDS [px][264] (xlp dead since barrier 2) ----
#pragma unroll
  for (int ci = 0; ci < 2; ++ci)
#pragma unroll
    for (int ni = 0; ni < 2; ++ni) {
      const int px = half * 32 + ni * 16 + l15;
      half4v h = {(half_t)oa[ci][ni].x, (half_t)oa[ci][ni].y,
                  (half_t)oa[ci][ni].z, (half_t)oa[ci][ni].w};
      *(half4v*)(xa + px * 264 + head * 32 + ci * 16 + quad * 4) = h;
    }
  __syncthreads();  // barrier 4: xa complete

  // ---- proj: wave owns o-rows [16*wave, +16), all 64 px ----
  float4v pacc[4];
#pragma unroll
  for (int ni = 0; ni < 4; ++ni) {
    float4v z = {0.f, 0.f, 0.f, 0.f};
    pacc[ni] = z;
  }
#pragma unroll
  for (int kh = 0; kh < 8; ++kh) {
    half8 af = *(const half8*)(pw + (wave * 16 + l15) * 256 + kh * 32 + quad * 8);
    half8 bf[4];
#pragma unroll
    for (int ni = 0; ni < 4; ++ni)
      bf[ni] = *(const half8*)&xa[(ni * 16 + l15) * 264 + kh * 32 + quad * 8];
#pragma unroll
    for (int ni = 0; ni < 4; ++ni)
      pacc[ni] = __builtin_amdgcn_mfma_f32_16x16x32_f16(af, bf[ni], pacc[ni], 0, 0, 0);
  }
  {
    const float4v b4 = *(const float4v*)&projb[wave * 16 + quad * 4];
#pragma unroll
    for (int ni = 0; ni < 4; ++ni) {
      pacc[ni].x += b4.x;
      pacc[ni].y += b4.y;
      pacc[ni].z += b4.z;
      pacc[ni].w += b4.w;
    }
  }

  // ---- transpose epilogue: 4 rounds of 64 o-rows via T[64][68] fp32 ----
  const int b = bd / 100, d = bd % 100;
  const size_t bdbase = (size_t)b * 1638400 + (size_t)d * 64;
  const int tr = tid >> 4;             // 0..63
  const int col0 = (tid & 15) * 4;
  for (int r = 0; r < 4; ++r) {
    __syncthreads();                   // r=0: also guards xa reads done
    if ((wave >> 2) == r) {
      const int rb = (wave & 3) * 16;
#pragma unroll
      for (int ni = 0; ni < 4; ++ni)
#pragma unroll
        for (int iv = 0; iv < 4; ++iv)
          T[(rb + quad * 4 + iv) * 68 + ni * 16 + l15] = pacc[ni][iv];
    }
    __syncthreads();
    const int o = r * 64 + tr;
    *(float4v*)(out32 + bdbase + (size_t)o * 6400 + col0) =
        *(const float4v*)&T[tr * 68 + col0];
  }
}

// ---------------- launch ----------------
extern "C" void kernel_launch(void* const* d_in, const int* in_sizes, int n_in,
                              void* d_out, int out_size, void* d_ws, size_t ws_size,
                              hipStream_t stream) {
  const float* x        = (const float*)d_in[0];
  const float* dwconv_w = (const float*)d_in[1];
  const float* dwconv_b = (const float*)d_in[2];
  const float* qkv_w    = (const float*)d_in[3];
  const float* qkv_b    = (const float*)d_in[4];
  const float* proj_w   = (const float*)d_in[5];
  const float* proj_b   = (const float*)d_in[6];
  const float* rpb      = (const float*)d_in[7];
  float* out = (float*)d_out;

  char* ws = (char*)d_ws;
  size_t off = 0;
  half_t* xpad = (half_t*)(ws + off); off += 40960000;   // 800*100*256 fp16
  half_t* xl   = (half_t*)(ws + off); off += 26214400;   // 51200*256 fp16
  half_t* Wt   = (half_t*)(ws + off); off += 1179648;    // [9][256][256]
  half_t* qw16 = (half_t*)(ws + off); off += 393216;
  half_t* pw16 = (half_t*)(ws + off); off += 131072;
  float*  btab = (float*)(ws + off);  off += 131072;     // [8][64][64]

  prep_all<<<1088, 256, 0, stream>>>(x, dwconv_w, qkv_w, proj_w, rpb,
                                     xpad, Wt, qw16, pw16, btab);
  conv_kernel<<<800, 256, 0, stream>>>(Wt, xpad, dwconv_b, xl);
  fused_tail5<<<800, 1024, 0, stream>>>(xl, qw16, qkv_b, btab, pw16, proj_b, out);
}